// Round 4
// baseline (209.568 us; speedup 1.0000x reference)
//
#include <hip/hip_runtime.h>
#include <hip/hip_fp16.h>
#include <stdint.h>

// Problem constants (B,C_IN,L fixed by the reference)
#define BB    4
#define CIN   512
#define CRED  256
#define LL    16384
#define NBLK  256      // L / 64
#define WELEM 131072   // elements per weight matrix (256*512)

typedef _Float16 half8 __attribute__((ext_vector_type(8)));
typedef float    f32x4 __attribute__((ext_vector_type(4)));

// ---------------- LDS byte layout (74 KB dynamic -> 2 blocks/CU) ----------
// Phase 1-2 : XT [64 pos][512 ch] fp16, rows 1024 B      0..65536
// After Bk  : Q  [64 pos][256 ch] fp16, rows 512 B       0..32768   (over XT)
//             K  [64 pos][256 ch] fp16, rows 512 B       32768..65536
// After B3  : XT re-staged (for V GEMM)                  0..65536   (over Q,K)
// After B5  : V  [256 ch][64 pos] fp16, rows 128 B       32768..65536 (over XT hi)
// After B6  : H  [64 pos][256 ch] fp16, rows 512 B       0..32768     (over XT lo)
// P  [64 i][64 j] fp16, rows 128 B                       65536..73728
// MSK 64 f32                                             73728..73984
#define XT_OFF 0
#define Q_OFF  0
#define K_OFF  32768
#define V_OFF  32768
#define H_OFF  0
#define P_OFF  65536
#define MSK_OFF 73728
#define LDS_BYTES 73984

// XOR swizzle at 16B granularity (safe for ds_read_b128); applied as
// byte_addr = linear_col ^ SWZ(row) on BOTH write and read sides.
#define SWZ(r) (((r)&7)<<4)

__global__ void convert_weights(const float* __restrict__ Wq,
                                const float* __restrict__ Wk,
                                const float* __restrict__ Wv,
                                const float* __restrict__ Wo,
                                _Float16* __restrict__ dst) {
    int i = blockIdx.x * blockDim.x + threadIdx.x;   // 0 .. 4*131072-1
    int m = i >> 17;
    int e = i & (WELEM - 1);
    const float* src = (m == 0) ? Wq : (m == 1) ? Wk : (m == 2) ? Wv : Wo;
    dst[(size_t)m * WELEM + e] = (_Float16)src[e];
}

__global__ __launch_bounds__(512, 4)
void att_fused(const float* __restrict__ x1, const float* __restrict__ mask,
               const _Float16* __restrict__ W,
               const float* __restrict__ bq, const float* __restrict__ bk,
               const float* __restrict__ bv, const float* __restrict__ bo,
               float* __restrict__ out) {
    extern __shared__ char lds[];
    const int tid  = threadIdx.x;
    const int wid  = tid >> 6;
    const int lane = tid & 63;
    const int l15  = lane & 15;
    const int l4   = lane >> 4;
    const int blk  = blockIdx.x;
    const int b    = blk >> 8;     // batch
    const int n    = blk & 255;    // 64-pos block
    const int jx   = tid & 15;     // staging: position quad
    const int rb   = tid >> 4;     // staging: channel-pair group 0..31

    const _Float16* Wq = W;
    const _Float16* Wk = W + WELEM;
    const _Float16* Wv = W + 2 * WELEM;
    const _Float16* Wo = W + 3 * WELEM;

    const float* xbase = x1 + ((size_t)b * CIN + 2 * rb) * LL + n * 64 + 4 * jx;

    // -------- Phase 1: stage X^T (pos-major, ch contiguous) + mask --------
    {
        #pragma unroll
        for (int i = 0; i < 8; ++i) {
            f32x4 a = *(const f32x4*)(xbase + (size_t)(64 * i) * LL);
            f32x4 c = *(const f32x4*)(xbase + (size_t)(64 * i + 1) * LL);
            const int col = 4 * rb + 128 * i;          // byte col = 2*ch
            #pragma unroll
            for (int u = 0; u < 4; ++u) {
                union { _Float16 h[2]; uint32_t w; } p;
                p.h[0] = (_Float16)a[u];
                p.h[1] = (_Float16)c[u];
                const int j = 4 * jx + u;
                *(uint32_t*)(lds + XT_OFF + j * 1024 + (col ^ SWZ(j))) = p.w;
            }
        }
        if (tid < 64)
            *(float*)(lds + MSK_OFF + tid * 4) = mask[(size_t)b * LL + n * 64 + tid];
    }
    __syncthreads();   // B0: XT ready

    // -------- Phase 2: Q,K = W @ X  (M=256, K=512, N=64), two 16-ch passes.
    // V deliberately NOT computed here: 3-op acc overflowed the 128-reg/wave
    // budget at 4 waves/EU (R3 spilled). Packed Q,K = 32 VGPRs only.
    uint64_t qh[2][4], kh[2][4];
    #pragma unroll
    for (int pass = 0; pass < 2; ++pass) {
        f32x4 aQ[4], aK[4];
        #pragma unroll
        for (int q = 0; q < 4; ++q) {
            aQ[q] = (f32x4){0.f, 0.f, 0.f, 0.f};
            aK[q] = (f32x4){0.f, 0.f, 0.f, 0.f};
        }
        const int mrow = wid * 32 + pass * 16 + l15;
        const _Float16* wqp = Wq + (size_t)mrow * CIN + l4 * 8;
        const _Float16* wkp = Wk + (size_t)mrow * CIN + l4 * 8;
        #pragma unroll 4
        for (int ks = 0; ks < 16; ++ks) {
            const int kb = ks * 64 + l4 * 16;
            half8 xb[4];
            #pragma unroll
            for (int nt = 0; nt < 4; ++nt) {
                const int j = nt * 16 + l15;
                xb[nt] = *(const half8*)(lds + XT_OFF + j * 1024 + (kb ^ SWZ(j)));
            }
            half8 aq = *(const half8*)(wqp + ks * 32);
            half8 ak = *(const half8*)(wkp + ks * 32);
            #pragma unroll
            for (int nt = 0; nt < 4; ++nt) {
                aQ[nt] = __builtin_amdgcn_mfma_f32_16x16x32_f16(aq, xb[nt], aQ[nt], 0, 0, 0);
                aK[nt] = __builtin_amdgcn_mfma_f32_16x16x32_f16(ak, xb[nt], aK[nt], 0, 0, 0);
            }
        }
        const int c0 = wid * 32 + pass * 16 + l4 * 4;
        f32x4 bqv = *(const f32x4*)(bq + c0);
        f32x4 bkv = *(const f32x4*)(bk + c0);
        #pragma unroll
        for (int nt = 0; nt < 4; ++nt) {
            union { _Float16 h[4]; uint64_t q; } qp, kp;
            #pragma unroll
            for (int ri = 0; ri < 4; ++ri) {
                qp.h[ri] = (_Float16)(aQ[nt][ri] + bqv[ri]);
                kp.h[ri] = (_Float16)(aK[nt][ri] + bkv[ri]);
            }
            qh[pass][nt] = qp.q;
            kh[pass][nt] = kp.q;
        }
    }
    __syncthreads();   // Bk: XT dead -> Q/K may overlay it

    // scatter Q,K (b64, [pos][ch])
    #pragma unroll
    for (int pass = 0; pass < 2; ++pass) {
        const int c0 = wid * 32 + pass * 16 + l4 * 4;
        #pragma unroll
        for (int nt = 0; nt < 4; ++nt) {
            const int j = nt * 16 + l15;
            *(uint64_t*)(lds + Q_OFF + j * 512 + ((2 * c0) ^ SWZ(j))) = qh[pass][nt];
            *(uint64_t*)(lds + K_OFF + j * 512 + ((2 * c0) ^ SWZ(j))) = kh[pass][nt];
        }
    }
    __syncthreads();   // Bqk: Q,K ready

    // -------- issue X re-stage loads NOW (T14): latency hides under S/softmax
    f32x4 rE[8], rO[8];
    #pragma unroll
    for (int i = 0; i < 8; ++i) {
        rE[i] = *(const f32x4*)(xbase + (size_t)(64 * i) * LL);
        rO[i] = *(const f32x4*)(xbase + (size_t)(64 * i + 1) * LL);
    }

    // -------- Phase 3+4: S = (Q^T K)*scale, in-register masked softmax, P --
    if (wid < 4) {
        const int i0 = wid * 16;
        f32x4 sa[4];
        #pragma unroll
        for (int jt = 0; jt < 4; ++jt) sa[jt] = (f32x4){0.f, 0.f, 0.f, 0.f};
        #pragma unroll
        for (int ks = 0; ks < 8; ++ks) {
            const int kb = ks * 64 + l4 * 16;
            const int iq = i0 + l15;
            half8 qa = *(const half8*)(lds + Q_OFF + iq * 512 + (kb ^ SWZ(iq)));
            #pragma unroll
            for (int jt = 0; jt < 4; ++jt) {
                const int jr = jt * 16 + l15;
                half8 kf = *(const half8*)(lds + K_OFF + jr * 512 + (kb ^ SWZ(jr)));
                sa[jt] = __builtin_amdgcn_mfma_f32_16x16x32_f16(qa, kf, sa[jt], 0, 0, 0);
            }
        }
        float msk[4];
        #pragma unroll
        for (int jt = 0; jt < 4; ++jt)
            msk[jt] = *(const float*)(lds + MSK_OFF + (jt * 16 + l15) * 4);
        // per-lane rows: i = i0 + l4*4 + ri ; cols: j = jt*16 + l15.
        #pragma unroll
        for (int ri = 0; ri < 4; ++ri) {
            float v[4];
            #pragma unroll
            for (int jt = 0; jt < 4; ++jt)
                v[jt] = (msk[jt] == 0.f) ? -1e30f : sa[jt][ri] * 0.0625f;
            float mx = fmaxf(fmaxf(v[0], v[1]), fmaxf(v[2], v[3]));
            mx = fmaxf(mx, __shfl_xor(mx, 1));
            mx = fmaxf(mx, __shfl_xor(mx, 2));
            mx = fmaxf(mx, __shfl_xor(mx, 4));
            mx = fmaxf(mx, __shfl_xor(mx, 8));
            float e[4], sum = 0.f;
            #pragma unroll
            for (int jt = 0; jt < 4; ++jt) { e[jt] = __expf(v[jt] - mx); sum += e[jt]; }
            sum += __shfl_xor(sum, 1);
            sum += __shfl_xor(sum, 2);
            sum += __shfl_xor(sum, 4);
            sum += __shfl_xor(sum, 8);
            const float inv = 1.f / sum;
            const int i = i0 + l4 * 4 + ri;
            #pragma unroll
            for (int jt = 0; jt < 4; ++jt) {
                const int j = jt * 16 + l15;
                *(_Float16*)(lds + P_OFF + i * 128 + ((2 * j) ^ SWZ(i))) =
                    (_Float16)(e[jt] * inv);
            }
        }
    }
    __syncthreads();   // B3: P ready; Q,K dead

    // -------- commit X re-stage (values already in flight) --------
    #pragma unroll
    for (int i = 0; i < 8; ++i) {
        const int col = 4 * rb + 128 * i;
        #pragma unroll
        for (int u = 0; u < 4; ++u) {
            union { _Float16 h[2]; uint32_t w; } p;
            p.h[0] = (_Float16)rE[i][u];
            p.h[1] = (_Float16)rO[i][u];
            const int j = 4 * jx + u;
            *(uint32_t*)(lds + XT_OFF + j * 1024 + (col ^ SWZ(j))) = p.w;
        }
    }
    __syncthreads();   // B4: XT ready again

    // -------- Phase 2b: V = Wv @ X  (M=256, K=512, N=64), single pass ------
    uint64_t vh[2][4];
    {
        f32x4 aV[2][4];
        #pragma unroll
        for (int m = 0; m < 2; ++m)
            #pragma unroll
            for (int q = 0; q < 4; ++q) aV[m][q] = (f32x4){0.f, 0.f, 0.f, 0.f};
        const _Float16* wvp = Wv + (size_t)(wid * 32 + l15) * CIN + l4 * 8;
        #pragma unroll 4
        for (int ks = 0; ks < 16; ++ks) {
            const int kb = ks * 64 + l4 * 16;
            half8 xb[4];
            #pragma unroll
            for (int nt = 0; nt < 4; ++nt) {
                const int j = nt * 16 + l15;
                xb[nt] = *(const half8*)(lds + XT_OFF + j * 1024 + (kb ^ SWZ(j)));
            }
            #pragma unroll
            for (int mt = 0; mt < 2; ++mt) {
                half8 av = *(const half8*)(wvp + mt * 16 * CIN + ks * 32);
                #pragma unroll
                for (int nt = 0; nt < 4; ++nt)
                    aV[mt][nt] = __builtin_amdgcn_mfma_f32_16x16x32_f16(av, xb[nt], aV[mt][nt], 0, 0, 0);
            }
        }
        #pragma unroll
        for (int mt = 0; mt < 2; ++mt) {
            const int c0 = wid * 32 + mt * 16 + l4 * 4;
            f32x4 bvv = *(const f32x4*)(bv + c0);
            #pragma unroll
            for (int nt = 0; nt < 4; ++nt) {
                union { _Float16 h[4]; uint64_t q; } vp;
                #pragma unroll
                for (int ri = 0; ri < 4; ++ri)
                    vp.h[ri] = (_Float16)(aV[mt][nt][ri] + bvv[ri]);
                vh[mt][nt] = vp.q;
            }
        }
    }
    __syncthreads();   // B5: XT dead -> V may overlay its upper half

    // scatter V (u16, [ch][pos])
    #pragma unroll
    for (int mt = 0; mt < 2; ++mt) {
        const int c0 = wid * 32 + mt * 16 + l4 * 4;
        #pragma unroll
        for (int nt = 0; nt < 4; ++nt) {
            const int j = nt * 16 + l15;
            const uint64_t v64 = vh[mt][nt];
            #pragma unroll
            for (int ri = 0; ri < 4; ++ri) {
                const int c = c0 + ri;
                *(uint16_t*)(lds + V_OFF + c * 128 + ((2 * j) ^ SWZ(c))) =
                    (uint16_t)(v64 >> (16 * ri));
            }
        }
    }
    __syncthreads();   // B6: V ready

    // -------- Phase 5: H = relu(V @ P^T)  (M=256 ch, N=64 i, K=64 j) ------
    {
        const int cb = wid * 32;
        f32x4 pv[2][4];
        #pragma unroll
        for (int m = 0; m < 2; ++m)
            #pragma unroll
            for (int q = 0; q < 4; ++q) pv[m][q] = (f32x4){0.f, 0.f, 0.f, 0.f};
        #pragma unroll
        for (int ks = 0; ks < 2; ++ks) {
            const int kb = ks * 64 + l4 * 16;
            half8 pb[4];
            #pragma unroll
            for (int nt = 0; nt < 4; ++nt) {
                const int i = nt * 16 + l15;
                pb[nt] = *(const half8*)(lds + P_OFF + i * 128 + (kb ^ SWZ(i)));
            }
            #pragma unroll
            for (int mt = 0; mt < 2; ++mt) {
                const int c = cb + mt * 16 + l15;
                half8 va = *(const half8*)(lds + V_OFF + c * 128 + (kb ^ SWZ(c)));
                #pragma unroll
                for (int nt = 0; nt < 4; ++nt)
                    pv[mt][nt] = __builtin_amdgcn_mfma_f32_16x16x32_f16(va, pb[nt], pv[mt][nt], 0, 0, 0);
            }
        }
        // relu + H [pos][ch] b64-packed into XT's lower half (dead)
        #pragma unroll
        for (int mt = 0; mt < 2; ++mt) {
            const int c0 = cb + mt * 16 + l4 * 4;
            #pragma unroll
            for (int nt = 0; nt < 4; ++nt) {
                const int j = nt * 16 + l15;
                union { _Float16 h[4]; uint64_t q; } hp;
                #pragma unroll
                for (int ri = 0; ri < 4; ++ri)
                    hp.h[ri] = (_Float16)fmaxf(pv[mt][nt][ri], 0.f);
                *(uint64_t*)(lds + H_OFF + j * 512 + ((2 * c0) ^ SWZ(j))) = hp.q;
            }
        }
    }
    __syncthreads();   // B7: H ready

    // -------- Phase 6: Out = Wo @ H + bo  (M=512, K=256, N=64) ------------
    {
        const int mbo = wid * 64;
        const _Float16* wob = Wo + (size_t)(mbo + l15) * CRED + l4 * 8;
        f32x4 oa[4][4];
        #pragma unroll
        for (int m = 0; m < 4; ++m)
            #pragma unroll
            for (int q = 0; q < 4; ++q) oa[m][q] = (f32x4){0.f, 0.f, 0.f, 0.f};
        #pragma unroll 4
        for (int ks = 0; ks < 8; ++ks) {
            const int kb = ks * 64 + l4 * 16;
            half8 hb[4];
            #pragma unroll
            for (int nt = 0; nt < 4; ++nt) {
                const int i = nt * 16 + l15;
                hb[nt] = *(const half8*)(lds + H_OFF + i * 512 + (kb ^ SWZ(i)));
            }
            #pragma unroll
            for (int mt = 0; mt < 4; ++mt) {
                half8 wa = *(const half8*)(wob + mt * 16 * CRED + ks * 32);
                #pragma unroll
                for (int nt = 0; nt < 4; ++nt)
                    oa[mt][nt] = __builtin_amdgcn_mfma_f32_16x16x32_f16(wa, hb[nt], oa[mt][nt], 0, 0, 0);
            }
        }
        #pragma unroll
        for (int mt = 0; mt < 4; ++mt) {
            const int o0 = mbo + mt * 16 + l4 * 4;
            f32x4 bov = *(const f32x4*)(bo + o0);
            #pragma unroll
            for (int ri = 0; ri < 4; ++ri) {
                float* orow = out + ((size_t)b * CIN + (o0 + ri)) * LL + n * 64;
                #pragma unroll
                for (int nt = 0; nt < 4; ++nt)
                    orow[nt * 16 + l15] = oa[mt][nt][ri] + bov[ri];
            }
        }
    }
}

extern "C" void kernel_launch(void* const* d_in, const int* in_sizes, int n_in,
                              void* d_out, int out_size, void* d_ws, size_t ws_size,
                              hipStream_t stream) {
    const float* x1   = (const float*)d_in[0];
    // d_in[1] = x2 : unused by the reference
    const float* mask = (const float*)d_in[2];
    const float* Wq   = (const float*)d_in[3];
    const float* bq   = (const float*)d_in[4];
    const float* Wk   = (const float*)d_in[5];
    const float* bk   = (const float*)d_in[6];
    const float* Wv   = (const float*)d_in[7];
    const float* bv   = (const float*)d_in[8];
    const float* Wo   = (const float*)d_in[9];
    const float* bo   = (const float*)d_in[10];
    float* out = (float*)d_out;
    _Float16* wbuf = (_Float16*)d_ws;   // 1 MB of fp16 weights

    (void)hipFuncSetAttribute((const void*)att_fused,
                              hipFuncAttributeMaxDynamicSharedMemorySize, LDS_BYTES);

    convert_weights<<<2048, 256, 0, stream>>>(Wq, Wk, Wv, Wo, wbuf);
    att_fused<<<BB * NBLK, 512, LDS_BYTES, stream>>>(x1, mask, wbuf, bq, bk, bv, bo, out);
}

// Round 5
// 167.928 us; speedup vs baseline: 1.2480x; 1.2480x over previous
//
#include <hip/hip_runtime.h>
#include <hip/hip_fp16.h>
#include <stdint.h>

// Problem constants (B,C_IN,L fixed by the reference)
#define BB    4
#define CIN   512
#define CRED  256
#define LL    16384
#define NBLK  256      // L / 64
#define WELEM 131072   // elements per weight matrix (256*512)

typedef _Float16 half8 __attribute__((ext_vector_type(8)));
typedef float    f32x4 __attribute__((ext_vector_type(4)));

// ---------------- LDS byte layout (74 KB -> 2 blocks/CU at 256 thr) -------
// Phase 1-2 : XT [64 pos][512 ch] fp16, rows 1024 B      0..65536
// After Bk  : Q  [64 pos][256 ch] fp16, rows 512 B       0..32768   (over XT)
//             K  [64 pos][256 ch] fp16, rows 512 B       32768..65536
// After B3  : V  [256 ch][64 pos] fp16, rows 128 B       32768..65536 (over K)
//             H  [64 pos][256 ch] fp16, rows 512 B       0..32768     (over Q)
// P  [64 i][64 j] fp16, rows 128 B                       65536..73728
// MSK 64 f32                                             73728..73984
#define XT_OFF 0
#define Q_OFF  0
#define K_OFF  32768
#define V_OFF  32768
#define H_OFF  0
#define P_OFF  65536
#define MSK_OFF 73728
#define LDS_BYTES 73984

// XOR swizzle at 16B granularity (safe for ds_read_b128); applied as
// byte_addr = linear_col ^ SWZ(row) on BOTH write and read sides.
#define SWZ(r) (((r)&7)<<4)

__global__ void convert_weights(const float* __restrict__ Wq,
                                const float* __restrict__ Wk,
                                const float* __restrict__ Wv,
                                const float* __restrict__ Wo,
                                _Float16* __restrict__ dst) {
    int i = blockIdx.x * blockDim.x + threadIdx.x;   // 0 .. 4*131072-1
    int m = i >> 17;
    int e = i & (WELEM - 1);
    const float* src = (m == 0) ? Wq : (m == 1) ? Wk : (m == 2) ? Wv : Wo;
    dst[(size_t)m * WELEM + e] = (_Float16)src[e];
}

// 256 threads (4 waves), min 2 waves/EU -> 256 unified regs/wave (no spill),
// 2 blocks/CU (74 KB LDS each) -> cross-block phase overlap.
__global__ __launch_bounds__(256, 2)
void att_fused(const float* __restrict__ x1, const float* __restrict__ mask,
               const _Float16* __restrict__ W,
               const float* __restrict__ bq, const float* __restrict__ bk,
               const float* __restrict__ bv, const float* __restrict__ bo,
               float* __restrict__ out) {
    extern __shared__ char lds[];
    const int tid  = threadIdx.x;
    const int wid  = tid >> 6;         // 0..3
    const int lane = tid & 63;
    const int l15  = lane & 15;
    const int l4   = lane >> 4;
    const int blk  = blockIdx.x;
    const int b    = blk >> 8;     // batch
    const int n    = blk & 255;    // 64-pos block
    const int jx   = tid & 15;     // staging: position quad
    const int rb   = tid >> 4;     // staging: channel-pair group 0..15

    const _Float16* Wq = W;
    const _Float16* Wk = W + WELEM;
    const _Float16* Wv = W + 2 * WELEM;
    const _Float16* Wo = W + 3 * WELEM;

    // -------- Phase 1: stage X^T (pos-major, ch contiguous) + mask --------
    {
        const float* xbase = x1 + ((size_t)b * CIN + 2 * rb) * LL + n * 64 + 4 * jx;
        #pragma unroll
        for (int i = 0; i < 16; ++i) {
            f32x4 a = *(const f32x4*)(xbase + (size_t)(32 * i) * LL);
            f32x4 c = *(const f32x4*)(xbase + (size_t)(32 * i + 1) * LL);
            const int col = 4 * rb + 64 * i;           // byte col = 2*ch
            #pragma unroll
            for (int u = 0; u < 4; ++u) {
                union { _Float16 h[2]; uint32_t w; } p;
                p.h[0] = (_Float16)a[u];
                p.h[1] = (_Float16)c[u];
                const int j = 4 * jx + u;
                *(uint32_t*)(lds + XT_OFF + j * 1024 + (col ^ SWZ(j))) = p.w;
            }
        }
        if (tid < 64)
            *(float*)(lds + MSK_OFF + tid * 4) = mask[(size_t)b * LL + n * 64 + tid];
    }
    __syncthreads();   // B0: XT ready

    // -------- Phase 2: Q,K,V = W @ X  (M=256, K=512, N=64) ----------------
    // Wave owns 64 channels; 4 passes x 16 ch keep acc at 48 regs. Packed
    // results (96 VGPRs) carried to their scatter points; fits 256-reg file.
    uint64_t qh[4][4], kh[4][4], vh[4][4];
    #pragma unroll
    for (int pass = 0; pass < 4; ++pass) {
        f32x4 aQ[4], aK[4], aV[4];
        #pragma unroll
        for (int q = 0; q < 4; ++q) {
            aQ[q] = (f32x4){0.f, 0.f, 0.f, 0.f};
            aK[q] = (f32x4){0.f, 0.f, 0.f, 0.f};
            aV[q] = (f32x4){0.f, 0.f, 0.f, 0.f};
        }
        const int mrow = wid * 64 + pass * 16 + l15;
        const _Float16* wqp = Wq + (size_t)mrow * CIN + l4 * 8;
        const _Float16* wkp = Wk + (size_t)mrow * CIN + l4 * 8;
        const _Float16* wvp = Wv + (size_t)mrow * CIN + l4 * 8;
        #pragma unroll 4
        for (int ks = 0; ks < 16; ++ks) {
            const int kb = ks * 64 + l4 * 16;
            half8 xb[4];
            #pragma unroll
            for (int nt = 0; nt < 4; ++nt) {
                const int j = nt * 16 + l15;
                xb[nt] = *(const half8*)(lds + XT_OFF + j * 1024 + (kb ^ SWZ(j)));
            }
            half8 aq = *(const half8*)(wqp + ks * 32);
            half8 ak = *(const half8*)(wkp + ks * 32);
            half8 av = *(const half8*)(wvp + ks * 32);
            #pragma unroll
            for (int nt = 0; nt < 4; ++nt) {
                aQ[nt] = __builtin_amdgcn_mfma_f32_16x16x32_f16(aq, xb[nt], aQ[nt], 0, 0, 0);
                aK[nt] = __builtin_amdgcn_mfma_f32_16x16x32_f16(ak, xb[nt], aK[nt], 0, 0, 0);
                aV[nt] = __builtin_amdgcn_mfma_f32_16x16x32_f16(av, xb[nt], aV[nt], 0, 0, 0);
            }
        }
        const int c0 = wid * 64 + pass * 16 + l4 * 4;
        f32x4 bqv = *(const f32x4*)(bq + c0);
        f32x4 bkv = *(const f32x4*)(bk + c0);
        f32x4 bvv = *(const f32x4*)(bv + c0);
        #pragma unroll
        for (int nt = 0; nt < 4; ++nt) {
            union { _Float16 h[4]; uint64_t q; } qp, kp, vp;
            #pragma unroll
            for (int ri = 0; ri < 4; ++ri) {
                qp.h[ri] = (_Float16)(aQ[nt][ri] + bqv[ri]);
                kp.h[ri] = (_Float16)(aK[nt][ri] + bkv[ri]);
                vp.h[ri] = (_Float16)(aV[nt][ri] + bvv[ri]);
            }
            qh[pass][nt] = qp.q;
            kh[pass][nt] = kp.q;
            vh[pass][nt] = vp.q;
        }
    }
    __syncthreads();   // Bk: XT dead -> Q/K may overlay it

    // scatter Q,K (b64, [pos][ch])
    #pragma unroll
    for (int pass = 0; pass < 4; ++pass) {
        const int c0 = wid * 64 + pass * 16 + l4 * 4;
        #pragma unroll
        for (int nt = 0; nt < 4; ++nt) {
            const int j = nt * 16 + l15;
            *(uint64_t*)(lds + Q_OFF + j * 512 + ((2 * c0) ^ SWZ(j))) = qh[pass][nt];
            *(uint64_t*)(lds + K_OFF + j * 512 + ((2 * c0) ^ SWZ(j))) = kh[pass][nt];
        }
    }
    __syncthreads();   // Bqk: Q,K ready

    // -------- Phase 3+4: S = (Q^T K)*scale, in-register masked softmax, P --
    {
        const int i0 = wid * 16;
        f32x4 sa[4];
        #pragma unroll
        for (int jt = 0; jt < 4; ++jt) sa[jt] = (f32x4){0.f, 0.f, 0.f, 0.f};
        #pragma unroll
        for (int ks = 0; ks < 8; ++ks) {
            const int kb = ks * 64 + l4 * 16;
            const int iq = i0 + l15;
            half8 qa = *(const half8*)(lds + Q_OFF + iq * 512 + (kb ^ SWZ(iq)));
            #pragma unroll
            for (int jt = 0; jt < 4; ++jt) {
                const int jr = jt * 16 + l15;
                half8 kf = *(const half8*)(lds + K_OFF + jr * 512 + (kb ^ SWZ(jr)));
                sa[jt] = __builtin_amdgcn_mfma_f32_16x16x32_f16(qa, kf, sa[jt], 0, 0, 0);
            }
        }
        float msk[4];
        #pragma unroll
        for (int jt = 0; jt < 4; ++jt)
            msk[jt] = *(const float*)(lds + MSK_OFF + (jt * 16 + l15) * 4);
        // per-lane rows: i = i0 + l4*4 + ri ; cols: j = jt*16 + l15.
        #pragma unroll
        for (int ri = 0; ri < 4; ++ri) {
            float v[4];
            #pragma unroll
            for (int jt = 0; jt < 4; ++jt)
                v[jt] = (msk[jt] == 0.f) ? -1e30f : sa[jt][ri] * 0.0625f;
            float mx = fmaxf(fmaxf(v[0], v[1]), fmaxf(v[2], v[3]));
            mx = fmaxf(mx, __shfl_xor(mx, 1));
            mx = fmaxf(mx, __shfl_xor(mx, 2));
            mx = fmaxf(mx, __shfl_xor(mx, 4));
            mx = fmaxf(mx, __shfl_xor(mx, 8));
            float e[4], sum = 0.f;
            #pragma unroll
            for (int jt = 0; jt < 4; ++jt) { e[jt] = __expf(v[jt] - mx); sum += e[jt]; }
            sum += __shfl_xor(sum, 1);
            sum += __shfl_xor(sum, 2);
            sum += __shfl_xor(sum, 4);
            sum += __shfl_xor(sum, 8);
            const float inv = 1.f / sum;
            const int i = i0 + l4 * 4 + ri;
            #pragma unroll
            for (int jt = 0; jt < 4; ++jt) {
                const int j = jt * 16 + l15;
                *(_Float16*)(lds + P_OFF + i * 128 + ((2 * j) ^ SWZ(i))) =
                    (_Float16)(e[jt] * inv);
            }
        }
    }
    __syncthreads();   // B3: P ready; Q,K dead

    // scatter V (u16, [ch][pos]) into K's old region
    #pragma unroll
    for (int pass = 0; pass < 4; ++pass) {
        const int c0 = wid * 64 + pass * 16 + l4 * 4;
        #pragma unroll
        for (int nt = 0; nt < 4; ++nt) {
            const int j = nt * 16 + l15;
            const uint64_t v64 = vh[pass][nt];
            #pragma unroll
            for (int ri = 0; ri < 4; ++ri) {
                const int c = c0 + ri;
                *(uint16_t*)(lds + V_OFF + c * 128 + ((2 * j) ^ SWZ(c))) =
                    (uint16_t)(v64 >> (16 * ri));
            }
        }
    }
    __syncthreads();   // B4: V ready

    // -------- Phase 5: H = relu(V @ P^T)  (M=256 ch, N=64 i, K=64 j) ------
    {
        const int cb = wid * 64;
        f32x4 pv[4][4];
        #pragma unroll
        for (int m = 0; m < 4; ++m)
            #pragma unroll
            for (int q = 0; q < 4; ++q) pv[m][q] = (f32x4){0.f, 0.f, 0.f, 0.f};
        #pragma unroll
        for (int ks = 0; ks < 2; ++ks) {
            const int kb = ks * 64 + l4 * 16;
            half8 pb[4];
            #pragma unroll
            for (int nt = 0; nt < 4; ++nt) {
                const int i = nt * 16 + l15;
                pb[nt] = *(const half8*)(lds + P_OFF + i * 128 + (kb ^ SWZ(i)));
            }
            #pragma unroll
            for (int mt = 0; mt < 4; ++mt) {
                const int c = cb + mt * 16 + l15;
                half8 va = *(const half8*)(lds + V_OFF + c * 128 + (kb ^ SWZ(c)));
                #pragma unroll
                for (int nt = 0; nt < 4; ++nt)
                    pv[mt][nt] = __builtin_amdgcn_mfma_f32_16x16x32_f16(va, pb[nt], pv[mt][nt], 0, 0, 0);
            }
        }
        // relu + H [pos][ch] b64-packed into Q's old region
        #pragma unroll
        for (int mt = 0; mt < 4; ++mt) {
            const int c0 = cb + mt * 16 + l4 * 4;
            #pragma unroll
            for (int nt = 0; nt < 4; ++nt) {
                const int j = nt * 16 + l15;
                union { _Float16 h[4]; uint64_t q; } hp;
                #pragma unroll
                for (int ri = 0; ri < 4; ++ri)
                    hp.h[ri] = (_Float16)fmaxf(pv[mt][nt][ri], 0.f);
                *(uint64_t*)(lds + H_OFF + j * 512 + ((2 * c0) ^ SWZ(j))) = hp.q;
            }
        }
    }
    __syncthreads();   // B5: H ready

    // -------- Phase 6: Out = Wo @ H + bo  (M=512, K=256, N=64) ------------
    // Wave owns 128 out-channels; 2 passes x 64 keep acc at 64 regs.
    #pragma unroll
    for (int op = 0; op < 2; ++op) {
        const int mbo = wid * 128 + op * 64;
        const _Float16* wob = Wo + (size_t)(mbo + l15) * CRED + l4 * 8;
        f32x4 oa[4][4];
        #pragma unroll
        for (int m = 0; m < 4; ++m)
            #pragma unroll
            for (int q = 0; q < 4; ++q) oa[m][q] = (f32x4){0.f, 0.f, 0.f, 0.f};
        #pragma unroll 4
        for (int ks = 0; ks < 8; ++ks) {
            const int kb = ks * 64 + l4 * 16;
            half8 hb[4];
            #pragma unroll
            for (int nt = 0; nt < 4; ++nt) {
                const int i = nt * 16 + l15;
                hb[nt] = *(const half8*)(lds + H_OFF + i * 512 + (kb ^ SWZ(i)));
            }
            #pragma unroll
            for (int mt = 0; mt < 4; ++mt) {
                half8 wa = *(const half8*)(wob + mt * 16 * CRED + ks * 32);
                #pragma unroll
                for (int nt = 0; nt < 4; ++nt)
                    oa[mt][nt] = __builtin_amdgcn_mfma_f32_16x16x32_f16(wa, hb[nt], oa[mt][nt], 0, 0, 0);
            }
        }
        #pragma unroll
        for (int mt = 0; mt < 4; ++mt) {
            const int o0 = mbo + mt * 16 + l4 * 4;
            f32x4 bov = *(const f32x4*)(bo + o0);
            #pragma unroll
            for (int ri = 0; ri < 4; ++ri) {
                float* orow = out + ((size_t)b * CIN + (o0 + ri)) * LL + n * 64;
                #pragma unroll
                for (int nt = 0; nt < 4; ++nt)
                    orow[nt * 16 + l15] = oa[mt][nt][ri] + bov[ri];
            }
        }
    }
}

extern "C" void kernel_launch(void* const* d_in, const int* in_sizes, int n_in,
                              void* d_out, int out_size, void* d_ws, size_t ws_size,
                              hipStream_t stream) {
    const float* x1   = (const float*)d_in[0];
    // d_in[1] = x2 : unused by the reference
    const float* mask = (const float*)d_in[2];
    const float* Wq   = (const float*)d_in[3];
    const float* bq   = (const float*)d_in[4];
    const float* Wk   = (const float*)d_in[5];
    const float* bk   = (const float*)d_in[6];
    const float* Wv   = (const float*)d_in[7];
    const float* bv   = (const float*)d_in[8];
    const float* Wo   = (const float*)d_in[9];
    const float* bo   = (const float*)d_in[10];
    float* out = (float*)d_out;
    _Float16* wbuf = (_Float16*)d_ws;   // 1 MB of fp16 weights

    (void)hipFuncSetAttribute((const void*)att_fused,
                              hipFuncAttributeMaxDynamicSharedMemorySize, LDS_BYTES);

    convert_weights<<<2048, 256, 0, stream>>>(Wq, Wk, Wv, Wo, wbuf);
    att_fused<<<BB * NBLK, 256, LDS_BYTES, stream>>>(x1, mask, wbuf, bq, bk, bv, bo, out);
}